// Round 3
// baseline (698.038 us; speedup 1.0000x reference)
//
#include <hip/hip_runtime.h>
#include <hip/hip_bf16.h>

typedef __hip_bfloat16 bf16;
typedef __attribute__((ext_vector_type(4))) float f32x4;
typedef __attribute__((ext_vector_type(8))) short bf16x8v;

static constexpr int   HD    = 768;
static constexpr int   NRr   = 8192;     // B*T
static constexpr int   SSAMP = 256;
static constexpr int   KTOP  = 64;
static constexpr int   NPOOL = 1024;
static constexpr float TINV  = 10.0f;    // 1/TEMP

__device__ __forceinline__ float bf2f(bf16 h){ return __bfloat162float(h); }
__device__ __forceinline__ bf16  f2bf(float f){ return __float2bfloat16(f); }

__device__ __forceinline__ float gelu_exact(float x){
  return 0.5f * x * (1.0f + erff(x * 0.70710678118654752f));
}

// deterministic block sum; buf must hold blockDim.x/64 floats
__device__ __forceinline__ float block_sum(float v, float* buf){
  const int lane = threadIdx.x & 63, w = threadIdx.x >> 6;
  const int nw = (int)blockDim.x >> 6;
  #pragma unroll
  for(int o = 32; o; o >>= 1) v += __shfl_down(v, o);
  __syncthreads();
  if(lane == 0) buf[w] = v;
  __syncthreads();
  float t = 0.f;
  for(int i = 0; i < nw; i++) t += buf[i];
  return t;
}

__device__ __forceinline__ void gload_lds16(const bf16* g, bf16* lds_uniform){
  __builtin_amdgcn_global_load_lds(
      (const __attribute__((address_space(1))) unsigned int*)(const void*)g,
      (__attribute__((address_space(3))) unsigned int*)(void*)lds_uniform,
      16, 0, 0);
}

// -------- weight transpose 768x768, f32 in -> bf16 out (W[k][n] -> Wt[n][k]) -
__global__ __launch_bounds__(256)
void transpose768(const float* __restrict__ Win, bf16* __restrict__ Wt){
  __shared__ float t[32][33];
  const int tx = threadIdx.x, ty = threadIdx.y;     // (32,8)
  const int bx = blockIdx.x * 32, by = blockIdx.y * 32;
  #pragma unroll
  for(int j = 0; j < 4; j++)
    t[ty + j*8][tx] = Win[(size_t)(by + ty + j*8) * HD + bx + tx];
  __syncthreads();
  #pragma unroll
  for(int j = 0; j < 4; j++)
    Wt[(size_t)(bx + ty + j*8) * HD + by + tx] = f2bf(t[tx][ty + j*8]);
}

// ---------------- LayerNorm (optionally + noise), f32 in -> bf16 out ---------
__global__ __launch_bounds__(256)
void ln_kernel(const float* __restrict__ x, const float* __restrict__ noise,
               const float* __restrict__ g1, const float* __restrict__ bb1,
               bf16* __restrict__ o1){
  __shared__ float buf[4];
  const int row = blockIdx.x, tid = threadIdx.x;
  const size_t base = (size_t)row * HD;
  float v[3];
  #pragma unroll
  for(int j = 0; j < 3; j++){
    const int i = tid + j*256;
    float t = x[base + i];
    if(noise) t += noise[base + i];
    v[j] = t;
  }
  float s = v[0] + v[1] + v[2];
  s = block_sum(s, buf);
  const float m = s * (1.0f / HD);
  float q = 0.f;
  #pragma unroll
  for(int j = 0; j < 3; j++){ const float d = v[j] - m; q += d*d; }
  q = block_sum(q, buf);
  const float inv = rsqrtf(q * (1.0f / HD) + 1e-5f);
  #pragma unroll
  for(int j = 0; j < 3; j++){
    const int i = tid + j*256;
    const float xh = (v[j] - m) * inv;
    o1[base + i] = f2bf(xh * g1[i] + bb1[i]);
  }
}

// ---------------- GEMM: C[M,N] = A[M,K] * Bt[N,K]^T, fused epilogues ---------
enum { EPI_GELU = 0, EPI_SCALE = 1, EPI_BIAS = 2, EPI_RAW = 3, EPI_LOGITS = 4 };

template<int EPI>
__global__ __launch_bounds__(256, 2)
void gemm_kernel(const bf16* __restrict__ A, const bf16* __restrict__ Bt,
                 const int M, const int N, const int K,
                 const float* __restrict__ bias,
                 bf16* __restrict__ outb, float* __restrict__ outf,
                 float* __restrict__ aux, float* __restrict__ aux2){
  __shared__ __align__(16) bf16 As[128 * 32];
  __shared__ __align__(16) bf16 Bs[128 * 32];
  __shared__ float rbuf[512];

  const int tid  = threadIdx.x;
  const int wave = tid >> 6, lane = tid & 63;
  const int wm = wave >> 1, wn = wave & 1;
  const int r16 = lane & 15, kh = lane >> 4;
  const int bx = blockIdx.x, by = blockIdx.y;
  const int row0 = by * 128, col0 = bx * 128;

  f32x4 acc[4][4];
  #pragma unroll
  for(int i = 0; i < 4; i++)
    #pragma unroll
    for(int j = 0; j < 4; j++){ f32x4 z = {0.f,0.f,0.f,0.f}; acc[i][j] = z; }

  // staging: tile 128x32 bf16 = 512 chunks of 16B, 256 threads x 2 chunks
  const int c0 = tid, c1 = tid + 256;
  const bf16* gA0 = A  + (size_t)(row0 + (c0 >> 2)) * K + (c0 & 3) * 8;
  const bf16* gA1 = A  + (size_t)(row0 + (c1 >> 2)) * K + (c1 & 3) * 8;
  const bf16* gB0 = Bt + (size_t)(col0 + (c0 >> 2)) * K + (c0 & 3) * 8;
  const bf16* gB1 = Bt + (size_t)(col0 + (c1 >> 2)) * K + (c1 & 3) * 8;
  bf16* lA0 = As + (wave * 64) * 8;          // wave-uniform LDS bases
  bf16* lA1 = As + (256 + wave * 64) * 8;
  bf16* lB0 = Bs + (wave * 64) * 8;
  bf16* lB1 = Bs + (256 + wave * 64) * 8;

  for(int k0 = 0; k0 < K; k0 += 32){
    __syncthreads();
    gload_lds16(gA0 + k0, lA0);
    gload_lds16(gA1 + k0, lA1);
    gload_lds16(gB0 + k0, lB0);
    gload_lds16(gB1 + k0, lB1);
    __syncthreads();
    bf16x8v av[4], bv[4];
    #pragma unroll
    for(int f = 0; f < 4; f++){
      av[f] = *(const bf16x8v*)(As + (wm*64 + f*16 + r16) * 32 + kh * 8);
      bv[f] = *(const bf16x8v*)(Bs + (wn*64 + f*16 + r16) * 32 + kh * 8);
    }
    #pragma unroll
    for(int i = 0; i < 4; i++)
      #pragma unroll
      for(int j = 0; j < 4; j++)
        acc[i][j] = __builtin_amdgcn_mfma_f32_16x16x32_bf16(av[i], bv[j], acc[i][j], 0, 0, 0);
  }

  const int crow0 = row0 + wm * 64;
  const int ccol0 = col0 + wn * 64;

  if constexpr(EPI != EPI_LOGITS){
    float part = 0.f;
    #pragma unroll
    for(int i = 0; i < 4; i++){
      #pragma unroll
      for(int j = 0; j < 4; j++){
        const int col = ccol0 + j*16 + r16;
        const float bvv = bias ? bias[col] : 0.f;
        #pragma unroll
        for(int q = 0; q < 4; q++){
          const int row = crow0 + i*16 + kh*4 + q;
          const float v = acc[i][j][q] + bvv;
          const size_t off = (size_t)row * N + col;
          if constexpr(EPI == EPI_GELU){
            outb[off] = f2bf(gelu_exact(v));
          } else if constexpr(EPI == EPI_SCALE){
            const float s = 1.0f + 0.25f * tanhf(v);
            outf[off] = s;
            const float d = s - 1.0f; part += d * d;
          } else if constexpr(EPI == EPI_BIAS){
            const float s = 0.25f * tanhf(v);
            outf[off] = s;
            part += s * s;
          } else {                      // EPI_RAW: bf16 out, l2norm later
            outb[off] = f2bf(v);
          }
        }
      }
    }
    if constexpr(EPI == EPI_SCALE || EPI == EPI_BIAS){
      const float tot = block_sum(part, rbuf);
      if(tid == 0) aux[(size_t)by * gridDim.x + bx] = tot;
    }
  } else {
    // logits tile: e = exp(10*acc); deterministic row/col partial sums
    float rs[16], cs[4];
    #pragma unroll
    for(int t = 0; t < 16; t++) rs[t] = 0.f;
    #pragma unroll
    for(int t = 0; t < 4; t++) cs[t] = 0.f;
    #pragma unroll
    for(int i = 0; i < 4; i++)
      #pragma unroll
      for(int j = 0; j < 4; j++)
        #pragma unroll
        for(int q = 0; q < 4; q++){
          const float ev = expf(acc[i][j][q] * TINV);
          rs[i*4 + q] += ev;
          cs[j]       += ev;
        }
    #pragma unroll
    for(int t = 0; t < 16; t++){
      float r = rs[t];
      r += __shfl_xor(r, 1); r += __shfl_xor(r, 2);
      r += __shfl_xor(r, 4); r += __shfl_xor(r, 8);
      rs[t] = r;
    }
    if(r16 == 0){
      #pragma unroll
      for(int i = 0; i < 4; i++)
        #pragma unroll
        for(int q = 0; q < 4; q++)
          rbuf[wn*128 + wm*64 + i*16 + kh*4 + q] = rs[i*4 + q];
    }
    #pragma unroll
    for(int j = 0; j < 4; j++){
      float c = cs[j];
      c += __shfl_xor(c, 16); c += __shfl_xor(c, 32);
      cs[j] = c;
    }
    if(kh == 0){
      #pragma unroll
      for(int j = 0; j < 4; j++)
        rbuf[256 + wm*128 + wn*64 + j*16 + r16] = cs[j];
    }
    __syncthreads();
    if(tid < 128){
      aux [(size_t)bx * M + row0 + tid] = rbuf[tid]       + rbuf[128 + tid];
      aux2[(size_t)by * M + col0 + tid] = rbuf[256 + tid] + rbuf[384 + tid];
    }
  }
}

// ---------------- aligned = scale*latent + bias (all f32) --------------------
__global__ __launch_bounds__(256)
void aligned_kernel(const float* __restrict__ latent, const float* __restrict__ sc,
                    const float* __restrict__ bi, float* __restrict__ outp){
  const size_t i4 = ((size_t)blockIdx.x * 256 + threadIdx.x) * 4;
  const float4 l = *(const float4*)(latent + i4);
  float4 o;
  o.x = sc[i4+0] * l.x + bi[i4+0];
  o.y = sc[i4+1] * l.y + bi[i4+1];
  o.z = sc[i4+2] * l.z + bi[i4+2];
  o.w = sc[i4+3] * l.w + bi[i4+3];
  *(float4*)(outp + i4) = o;
}

// ---------------- in-place row l2-normalize (bf16) ---------------------------
__global__ __launch_bounds__(256)
void l2n_kernel(bf16* __restrict__ vio){
  __shared__ float buf[4];
  const int row = blockIdx.x, tid = threadIdx.x;
  const size_t base = (size_t)row * HD;
  float v[3];
  #pragma unroll
  for(int j = 0; j < 3; j++) v[j] = bf2f(vio[base + tid + j*256]);
  float q = v[0]*v[0] + v[1]*v[1] + v[2]*v[2];
  q = block_sum(q, buf);
  const float inv = 1.0f / fmaxf(sqrtf(q), 1e-12f);
  #pragma unroll
  for(int j = 0; j < 3; j++) vio[base + tid + j*256] = f2bf(v[j] * inv);
}

// ---------------- diag_i = 10 * dot(va_i, vb_i) ------------------------------
__global__ __launch_bounds__(256)
void diag_kernel(const bf16* __restrict__ va, const bf16* __restrict__ vb,
                 float* __restrict__ diag){
  const int lane = threadIdx.x & 63;
  const int row = blockIdx.x * 4 + (threadIdx.x >> 6);
  const size_t base = (size_t)row * HD;
  float d = 0.f;
  #pragma unroll
  for(int j = 0; j < 12; j++){
    const int i = lane + j*64;
    d += bf2f(va[base + i]) * bf2f(vb[base + i]);
  }
  #pragma unroll
  for(int o = 32; o; o >>= 1) d += __shfl_down(d, o);
  if(lane == 0) diag[row] = d * TINV;
}

// ---------------- sum 64 partials per row/col --------------------------------
__global__ __launch_bounds__(256)
void rcsum_kernel(const float* __restrict__ rp, const float* __restrict__ cp,
                  float* __restrict__ rs, float* __restrict__ cs, const int nb){
  const int i = blockIdx.x * 256 + threadIdx.x;
  float r = 0.f, c = 0.f;
  for(int b = 0; b < nb; b++){
    r += rp[(size_t)b * NRr + i];
    c += cp[(size_t)b * NRr + i];
  }
  rs[i] = r; cs[i] = c;
}

// ---------------- gather sampled rows (f32), raw + normalized ----------------
__global__ __launch_bounds__(256)
void af_kernel(const float* __restrict__ aligned, const int* __restrict__ samp,
               float* __restrict__ afraw, float* __restrict__ afn){
  __shared__ float buf[4];
  const int s = blockIdx.x, tid = threadIdx.x;
  const size_t src = (size_t)samp[s] * HD, dst = (size_t)s * HD;
  float v[3];
  #pragma unroll
  for(int j = 0; j < 3; j++){
    const int i = tid + j*256;
    v[j] = aligned[src + i];
    afraw[dst + i] = v[j];
  }
  float q = v[0]*v[0] + v[1]*v[1] + v[2]*v[2];
  q = block_sum(q, buf);
  const float inv = 1.0f / fmaxf(sqrtf(q), 1e-12f);
  #pragma unroll
  for(int j = 0; j < 3; j++) afn[dst + tid + j*256] = v[j] * inv;
}

// ---------------- gather token pool rows (f32) + inverse norms ---------------
__global__ __launch_bounds__(256)
void te_kernel(const float* __restrict__ emb, const int* __restrict__ tok,
               float* __restrict__ teg, float* __restrict__ tenorminv){
  __shared__ float buf[4];
  const int p = blockIdx.x, tid = threadIdx.x;
  const size_t src = (size_t)tok[p] * HD, dst = (size_t)p * HD;
  float v[3];
  #pragma unroll
  for(int j = 0; j < 3; j++){
    const int i = tid + j*256;
    v[j] = emb[src + i];
    teg[dst + i] = v[j];
  }
  float q = v[0]*v[0] + v[1]*v[1] + v[2]*v[2];
  q = block_sum(q, buf);
  if(tid == 0) tenorminv[p] = 1.0f / fmaxf(sqrtf(q), 1e-12f);
}

// ---------------- tl[s][c] = 10 * dot(afn[s], teg[c]) * tenorminv[c] ---------
__global__ __launch_bounds__(256)
void tl_kernel(const float* __restrict__ afn, const float* __restrict__ teg,
               const float* __restrict__ tenorminv, float* __restrict__ tl){
  __shared__ float saf[HD];
  const int s = blockIdx.x, tid = threadIdx.x;
  #pragma unroll
  for(int j = 0; j < 3; j++) saf[tid + j*256] = afn[(size_t)s * HD + tid + j*256];
  __syncthreads();
  #pragma unroll
  for(int cb = 0; cb < 4; cb++){
    const int c = tid + cb * 256;
    const float* tr = teg + (size_t)c * HD;
    float d = 0.f;
    for(int k = 0; k < HD; k += 4){
      const float4 e = *(const float4*)(tr + k);
      d += e.x * saf[k] + e.y * saf[k+1] + e.z * saf[k+2] + e.w * saf[k+3];
    }
    tl[(size_t)s * NPOOL + c] = d * TINV * tenorminv[c];
  }
}

// ---------------- per-row top-64 -> softmax -> proto -> (af-proto)^2 ---------
__global__ __launch_bounds__(256)
void topk_kernel(const float* __restrict__ tl, const float* __restrict__ teg,
                 const float* __restrict__ afraw, float* __restrict__ protopart){
  __shared__ float sv[NPOOL];
  __shared__ float topv[KTOP];
  __shared__ int   topi[KTOP];
  __shared__ float wts[KTOP];
  __shared__ float rv[4];
  __shared__ int   ri[4];
  __shared__ float buf[4];
  __shared__ float sinv;
  const int s = blockIdx.x, tid = threadIdx.x;
  const int lane = tid & 63, w = tid >> 6;
  #pragma unroll
  for(int j = 0; j < 4; j++) sv[tid + j*256] = tl[(size_t)s * NPOOL + tid + j*256];
  __syncthreads();
  for(int k = 0; k < KTOP; k++){
    float bvv = -1e30f; int bi = 0x7fffffff;
    #pragma unroll
    for(int j = 0; j < 4; j++){
      const int i = tid + j*256;
      const float x = sv[i];
      if(x > bvv || (x == bvv && i < bi)){ bvv = x; bi = i; }
    }
    #pragma unroll
    for(int o = 1; o < 64; o <<= 1){
      const float ov = __shfl_xor(bvv, o);
      const int   oi = __shfl_xor(bi, o);
      if(ov > bvv || (ov == bvv && oi < bi)){ bvv = ov; bi = oi; }
    }
    if(lane == 0){ rv[w] = bvv; ri[w] = bi; }
    __syncthreads();
    if(tid == 0){
      for(int w2 = 1; w2 < 4; w2++)
        if(rv[w2] > bvv || (rv[w2] == bvv && ri[w2] < bi)){ bvv = rv[w2]; bi = ri[w2]; }
      if(bi < 0 || bi >= NPOOL) bi = 0;   // NaN-safe: never write OOB
      topv[k] = bvv; topi[k] = bi; sv[bi] = -1e30f;
    }
    __syncthreads();
  }
  if(tid < KTOP) wts[tid] = expf(topv[tid] - topv[0]);
  __syncthreads();
  if(tid == 0){
    float t = 0.f;
    for(int k = 0; k < KTOP; k++) t += wts[k];
    sinv = 1.0f / t;
  }
  __syncthreads();
  float part = 0.f;
  #pragma unroll
  for(int j = 0; j < 3; j++){
    const int h = tid + j*256;
    float ph = 0.f;
    for(int k = 0; k < KTOP; k++) ph += wts[k] * teg[(size_t)topi[k] * HD + h];
    ph *= sinv;
    const float d = afraw[(size_t)s * HD + h] - ph;
    part += d * d;
  }
  part = block_sum(part, buf);
  if(tid == 0) protopart[s] = part;
}

// ---------------- column moments of af (256 rows) and te (1024 rows) ---------
__global__ __launch_bounds__(768)
void mom_kernel(const float* __restrict__ afraw, const float* __restrict__ teg,
                float* __restrict__ mom){
  __shared__ float buf[12];
  const int h = threadIdx.x;
  float sa = 0.f, sa2 = 0.f;
  for(int s = 0; s < SSAMP; s++){
    const float v = afraw[(size_t)s * HD + h];
    sa += v; sa2 += v * v;
  }
  const float ma  = sa * (1.0f / SSAMP);
  const float sda = sqrtf(fmaxf(sa2 * (1.0f / SSAMP) - ma * ma, 0.f));
  float st = 0.f, st2 = 0.f;
  for(int p = 0; p < NPOOL; p++){
    const float v = teg[(size_t)p * HD + h];
    st += v; st2 += v * v;
  }
  const float mt  = st * (1.0f / NPOOL);
  const float sdt = sqrtf(fmaxf(st2 * (1.0f / NPOOL) - mt * mt, 0.f));
  const float dmu = ma - mt, dsd = sda - sdt;
  const float t1 = block_sum(dmu * dmu, buf);
  const float t2 = block_sum(dsd * dsd, buf);
  if(h == 0){ mom[0] = t1; mom[1] = t2; }
}

// ---------------- final scalars (f32 out) ------------------------------------
__global__ __launch_bounds__(1024)
void final_kernel(const float* __restrict__ rs, const float* __restrict__ cs,
                  const float* __restrict__ diag,
                  const float* __restrict__ auxs, const float* __restrict__ auxb,
                  const int naux,
                  const float* __restrict__ protopart, const float* __restrict__ mom,
                  float* __restrict__ outsc){
  __shared__ float buf[16];
  const int tid = threadIdx.x;
  float s1 = 0.f, s2 = 0.f;
  for(int r = tid; r < NRr; r += 1024){
    const float dg = diag[r];
    s1 += logf(rs[r]) - dg;
    s2 += logf(cs[r]) - dg;
  }
  float c1 = 0.f, c2 = 0.f;
  for(int j = tid; j < naux; j += 1024){ c1 += auxs[j]; c2 += auxb[j]; }
  float pp = 0.f;
  for(int j = tid; j < SSAMP; j += 1024) pp += protopart[j];
  s1 = block_sum(s1, buf);
  s2 = block_sum(s2, buf);
  c1 = block_sum(c1, buf);
  c2 = block_sum(c2, buf);
  pp = block_sum(pp, buf);
  if(tid == 0){
    const float con  = 0.5f * (s1 + s2) / (float)NRr;
    const float creg = (c1 + c2) / 6291456.0f;
    const float tdl  = pp / (float)(SSAMP * HD) + 0.1f * ((mom[0] + mom[1]) / (float)HD);
    outsc[0] = con;
    outsc[1] = tdl;
    outsc[2] = creg;
  }
}

// =================================================================== host ====
extern "C" void kernel_launch(void* const* d_in, const int* in_sizes, int n_in,
                              void* d_out, int out_size, void* d_ws, size_t ws_size,
                              hipStream_t stream){
  (void)in_sizes; (void)n_in; (void)out_size; (void)ws_size;
  const float* latent = (const float*)d_in[0];
  const float* tokemb = (const float*)d_in[1];
  const float* s_g  = (const float*)d_in[2];  const float* s_bln = (const float*)d_in[3];
  const float* s_w1 = (const float*)d_in[4];  const float* s_b1  = (const float*)d_in[5];
  const float* s_w2 = (const float*)d_in[6];  const float* s_b2  = (const float*)d_in[7];
  const float* b_g  = (const float*)d_in[8];  const float* b_bln = (const float*)d_in[9];
  const float* b_w1 = (const float*)d_in[10]; const float* b_b1  = (const float*)d_in[11];
  const float* b_w2 = (const float*)d_in[12]; const float* b_b2  = (const float*)d_in[13];
  const float* c_g  = (const float*)d_in[14]; const float* c_bln = (const float*)d_in[15];
  const float* c_w1 = (const float*)d_in[16]; const float* c_b1  = (const float*)d_in[17];
  const float* c_w2 = (const float*)d_in[18]; const float* c_b2  = (const float*)d_in[19];
  const float* noise_a = (const float*)d_in[20];
  const float* noise_b = (const float*)d_in[21];
  const int*  samp = (const int*)d_in[22];
  const int*  tok  = (const int*)d_in[23];

  float* out = (float*)d_out;
  float* out_aligned = out;                                   // [NRr*HD]
  float* out_scalars = out + (size_t)NRr * HD;                // [3]
  float* out_scale   = out + (size_t)NRr * HD + 3;            // [NRr*HD]
  float* out_bias    = out_scale + (size_t)NRr * HD;          // [NRr*HD]

  // ---- workspace layout (~67.5 MB, mirrors round-2 footprint) ----
  char* wp = (char*)d_ws;
  auto alloc = [&](size_t bytes) -> char* {
    char* p = wp; wp += (bytes + 255) & ~(size_t)255; return p;
  };
  bf16* wt_s1 = (bf16*)alloc((size_t)HD*HD*2);
  bf16* wt_s2 = (bf16*)alloc((size_t)HD*HD*2);
  bf16* wt_b1 = (bf16*)alloc((size_t)HD*HD*2);
  bf16* wt_b2 = (bf16*)alloc((size_t)HD*HD*2);
  bf16* wt_c1 = (bf16*)alloc((size_t)HD*HD*2);
  bf16* wt_c2 = (bf16*)alloc((size_t)HD*HD*2);
  bf16* X     = (bf16*)alloc((size_t)NRr*HD*2);   // ln output (reused 4x)
  bf16* Y     = (bf16*)alloc((size_t)NRr*HD*2);   // hidden (reused 4x)
  bf16* va    = (bf16*)alloc((size_t)NRr*HD*2);
  bf16* vb    = (bf16*)alloc((size_t)NRr*HD*2);
  float* rowpart = (float*)alloc((size_t)64*NRr*4);
  float* colpart = (float*)alloc((size_t)64*NRr*4);
  float* rowsum  = (float*)alloc((size_t)NRr*4);
  float* colsum  = (float*)alloc((size_t)NRr*4);
  float* diag    = (float*)alloc((size_t)NRr*4);
  float* aux1    = (float*)alloc(384*4);
  float* aux2    = (float*)alloc(384*4);
  float* afraw   = (float*)alloc((size_t)SSAMP*HD*4);
  float* afn     = (float*)alloc((size_t)SSAMP*HD*4);
  float* teg     = (float*)alloc((size_t)NPOOL*HD*4);
  float* tenorminv = (float*)alloc(NPOOL*4);
  float* tlb     = (float*)alloc((size_t)SSAMP*NPOOL*4);
  float* protopart = (float*)alloc(SSAMP*4);
  float* mom     = (float*)alloc(2*4);

  const dim3 tb(32, 8);
  const dim3 tg(24, 24);
  transpose768<<<tg, tb, 0, stream>>>(s_w1, wt_s1);
  transpose768<<<tg, tb, 0, stream>>>(s_w2, wt_s2);
  transpose768<<<tg, tb, 0, stream>>>(b_w1, wt_b1);
  transpose768<<<tg, tb, 0, stream>>>(b_w2, wt_b2);
  transpose768<<<tg, tb, 0, stream>>>(c_w1, wt_c1);
  transpose768<<<tg, tb, 0, stream>>>(c_w2, wt_c2);

  const dim3 gh(HD / 128, NRr / 128);          // (6,64)
  // scale head
  ln_kernel<<<NRr, 256, 0, stream>>>(latent, nullptr, s_g, s_bln, X);
  gemm_kernel<EPI_GELU ><<<gh, 256, 0, stream>>>(X, wt_s1, NRr, HD, HD, s_b1, Y, nullptr, nullptr, nullptr);
  gemm_kernel<EPI_SCALE><<<gh, 256, 0, stream>>>(Y, wt_s2, NRr, HD, HD, s_b2, nullptr, out_scale, aux1, nullptr);
  // bias head
  ln_kernel<<<NRr, 256, 0, stream>>>(latent, nullptr, b_g, b_bln, X);
  gemm_kernel<EPI_GELU ><<<gh, 256, 0, stream>>>(X, wt_b1, NRr, HD, HD, b_b1, Y, nullptr, nullptr, nullptr);
  gemm_kernel<EPI_BIAS ><<<gh, 256, 0, stream>>>(Y, wt_b2, NRr, HD, HD, b_b2, nullptr, out_bias, aux2, nullptr);
  aligned_kernel<<<(NRr * HD) / (256 * 4), 256, 0, stream>>>(latent, out_scale, out_bias, out_aligned);

  // contrastive head a
  ln_kernel<<<NRr, 256, 0, stream>>>(out_aligned, noise_a, c_g, c_bln, X);
  gemm_kernel<EPI_GELU><<<gh, 256, 0, stream>>>(X, wt_c1, NRr, HD, HD, c_b1, Y, nullptr, nullptr, nullptr);
  gemm_kernel<EPI_RAW ><<<gh, 256, 0, stream>>>(Y, wt_c2, NRr, HD, HD, c_b2, va, nullptr, nullptr, nullptr);
  l2n_kernel<<<NRr, 256, 0, stream>>>(va);
  // contrastive head b
  ln_kernel<<<NRr, 256, 0, stream>>>(out_aligned, noise_b, c_g, c_bln, X);
  gemm_kernel<EPI_GELU><<<gh, 256, 0, stream>>>(X, wt_c1, NRr, HD, HD, c_b1, Y, nullptr, nullptr, nullptr);
  gemm_kernel<EPI_RAW ><<<gh, 256, 0, stream>>>(Y, wt_c2, NRr, HD, HD, c_b2, vb, nullptr, nullptr, nullptr);
  l2n_kernel<<<NRr, 256, 0, stream>>>(vb);

  // streaming logits LSE
  const dim3 gl(NRr / 128, NRr / 128);         // (64,64)
  gemm_kernel<EPI_LOGITS><<<gl, 256, 0, stream>>>(va, vb, NRr, NRr, HD, nullptr, nullptr, nullptr, rowpart, colpart);
  rcsum_kernel<<<NRr / 256, 256, 0, stream>>>(rowpart, colpart, rowsum, colsum, NRr / 128);
  diag_kernel<<<NRr / 4, 256, 0, stream>>>(va, vb, diag);

  // token distribution path
  af_kernel<<<SSAMP, 256, 0, stream>>>(out_aligned, samp, afraw, afn);
  te_kernel<<<NPOOL, 256, 0, stream>>>(tokemb, tok, teg, tenorminv);
  tl_kernel<<<SSAMP, 256, 0, stream>>>(afn, teg, tenorminv, tlb);
  topk_kernel<<<SSAMP, 256, 0, stream>>>(tlb, teg, afraw, protopart);
  mom_kernel<<<1, 768, 0, stream>>>(afraw, teg, mom);

  final_kernel<<<1, 1024, 0, stream>>>(rowsum, colsum, diag, aux1, aux2, 384,
                                       protopart, mom, out_scalars);
}

// Round 4
// 674.464 us; speedup vs baseline: 1.0350x; 1.0350x over previous
//
#include <hip/hip_runtime.h>
#include <hip/hip_bf16.h>

typedef __hip_bfloat16 bf16;
typedef __attribute__((ext_vector_type(4))) float f32x4;
typedef __attribute__((ext_vector_type(8))) short bf16x8v;

static constexpr int   HD    = 768;
static constexpr int   NRr   = 8192;     // B*T
static constexpr int   SSAMP = 256;
static constexpr int   KTOP  = 64;
static constexpr int   NPOOL = 1024;
static constexpr float TINV  = 10.0f;    // 1/TEMP

__device__ __forceinline__ float bf2f(bf16 h){ return __bfloat162float(h); }
__device__ __forceinline__ bf16  f2bf(float f){ return __float2bfloat16(f); }

__device__ __forceinline__ float gelu_exact(float x){
  return 0.5f * x * (1.0f + erff(x * 0.70710678118654752f));
}

// deterministic block sum; buf must hold blockDim.x/64 floats
__device__ __forceinline__ float block_sum(float v, float* buf){
  const int lane = threadIdx.x & 63, w = threadIdx.x >> 6;
  const int nw = (int)blockDim.x >> 6;
  #pragma unroll
  for(int o = 32; o; o >>= 1) v += __shfl_down(v, o);
  __syncthreads();
  if(lane == 0) buf[w] = v;
  __syncthreads();
  float t = 0.f;
  for(int i = 0; i < nw; i++) t += buf[i];
  return t;
}

__device__ __forceinline__ void gload_lds16(const bf16* g, bf16* lds_uniform){
  __builtin_amdgcn_global_load_lds(
      (const __attribute__((address_space(1))) unsigned int*)(const void*)g,
      (__attribute__((address_space(3))) unsigned int*)(void*)lds_uniform,
      16, 0, 0);
}

// ---- transpose 768x768 with optional gain fold: Wt[n][k] = g[k]*W[k][n] -----
__global__ __launch_bounds__(256)
void tscale768(const float* __restrict__ Win, const float* __restrict__ g,
               bf16* __restrict__ Wt){
  __shared__ float t[32][33];
  const int tx = threadIdx.x, ty = threadIdx.y;     // (32,8)
  const int bx = blockIdx.x * 32, by = blockIdx.y * 32;
  #pragma unroll
  for(int j = 0; j < 4; j++)
    t[ty + j*8][tx] = Win[(size_t)(by + ty + j*8) * HD + bx + tx];
  __syncthreads();
  const float gv = g ? g[by + tx] : 1.0f;
  #pragma unroll
  for(int j = 0; j < 4; j++)
    Wt[(size_t)(bx + ty + j*8) * HD + by + tx] = f2bf(gv * t[tx][ty + j*8]);
}

// ---- folded bias: out[n] = b1[n] + sum_k bln[k]*w1[k][n] --------------------
__global__ __launch_bounds__(256)
void foldbias(const float* __restrict__ bln, const float* __restrict__ w1,
              const float* __restrict__ b1, float* __restrict__ outp){
  const int n = blockIdx.x * 256 + threadIdx.x;
  float t = b1[n];
  for(int k = 0; k < HD; k++) t += bln[k] * w1[(size_t)k * HD + n];
  outp[n] = t;
}

// ---- LayerNorm core xh=(x-m)/sigma (affine folded into weights), f32->bf16 --
// if na!=null: stacked mode, row<NRr uses na, else nb; src row = row & (NRr-1)
__global__ __launch_bounds__(256)
void lnxh_kernel(const float* __restrict__ x, const float* __restrict__ na,
                 const float* __restrict__ nb, bf16* __restrict__ o){
  __shared__ float buf[4];
  const int row = blockIdx.x, tid = threadIdx.x;
  const float* noise = nullptr;
  if(na) noise = (row < NRr) ? na : nb;
  const size_t srow = (size_t)(row & (NRr - 1)) * HD;
  const size_t nrow = noise ? ((size_t)(row & (NRr - 1)) * HD) : 0;
  const size_t drow = (size_t)row * HD;
  float v[3];
  #pragma unroll
  for(int j = 0; j < 3; j++){
    const int i = tid + j*256;
    float t = x[srow + i];
    if(noise) t += noise[nrow + i];
    v[j] = t;
  }
  float s = v[0] + v[1] + v[2];
  s = block_sum(s, buf);
  const float m = s * (1.0f / HD);
  float q = 0.f;
  #pragma unroll
  for(int j = 0; j < 3; j++){ const float d = v[j] - m; q += d*d; }
  q = block_sum(q, buf);
  const float inv = rsqrtf(q * (1.0f / HD) + 1e-5f);
  #pragma unroll
  for(int j = 0; j < 3; j++)
    o[drow + tid + j*256] = f2bf((v[j] - m) * inv);
}

// ---------------- GEMM: C[M,N] = A[M,K] * Bt[N,K]^T, fused epilogues ---------
enum { EPI_GELU = 0, EPI_SB = 1, EPI_RAW = 3, EPI_LOGITS = 4, EPI_TL = 5 };

template<int EPI>
__global__ __launch_bounds__(256, 2)
void gemm_kernel(const bf16* __restrict__ A, const bf16* __restrict__ Bt,
                 const bf16* __restrict__ Bt2,
                 const int M, const int N, const int K,
                 const int lda, const int ldc,
                 const float* __restrict__ bias, const float* __restrict__ bias2,
                 bf16* __restrict__ outb, float* __restrict__ outf,
                 float* __restrict__ outf2,
                 float* __restrict__ aux, float* __restrict__ aux2){
  __shared__ __align__(16) bf16 As[128 * 32];
  __shared__ __align__(16) bf16 Bs[128 * 32];
  __shared__ float rbuf[512];

  const int tid  = threadIdx.x;
  const int wave = tid >> 6, lane = tid & 63;
  const int wm = wave >> 1, wn = wave & 1;
  const int r16 = lane & 15, kh = lane >> 4;

  // XCD-aware bijective swizzle (grids here always have tot % 8 == 0)
  int bx = blockIdx.x, by = blockIdx.y;
  {
    const int gx = gridDim.x;
    const int tot = gx * gridDim.y;
    if((tot & 7) == 0){
      const int flat = by * gx + bx;
      const int cpx = tot >> 3;
      const int swz = (flat & 7) * cpx + (flat >> 3);
      by = swz / gx; bx = swz - by * gx;
    }
  }
  const int row0 = by * 128, col0 = bx * 128;

  float addv = 0.f;
  if constexpr(EPI == EPI_SB){
    if(blockIdx.z == 0){ addv = 1.0f; }
    else { A += 768; Bt = Bt2; bias = bias2; outf = outf2; }
  }

  f32x4 acc[4][4];
  #pragma unroll
  for(int i = 0; i < 4; i++)
    #pragma unroll
    for(int j = 0; j < 4; j++){ f32x4 z = {0.f,0.f,0.f,0.f}; acc[i][j] = z; }

  // staging: tile 128x32 bf16 = 512 chunks of 16B, 256 threads x 2 chunks
  const int c0 = tid, c1 = tid + 256;
  const bf16* gA0 = A  + (size_t)(row0 + (c0 >> 2)) * lda + (c0 & 3) * 8;
  const bf16* gA1 = A  + (size_t)(row0 + (c1 >> 2)) * lda + (c1 & 3) * 8;
  const bf16* gB0 = Bt + (size_t)(col0 + (c0 >> 2)) * K + (c0 & 3) * 8;
  const bf16* gB1 = Bt + (size_t)(col0 + (c1 >> 2)) * K + (c1 & 3) * 8;
  bf16* lA0 = As + (wave * 64) * 8;          // wave-uniform LDS bases
  bf16* lA1 = As + (256 + wave * 64) * 8;
  bf16* lB0 = Bs + (wave * 64) * 8;
  bf16* lB1 = Bs + (256 + wave * 64) * 8;

  for(int k0 = 0; k0 < K; k0 += 32){
    __syncthreads();
    gload_lds16(gA0 + k0, lA0);
    gload_lds16(gA1 + k0, lA1);
    gload_lds16(gB0 + k0, lB0);
    gload_lds16(gB1 + k0, lB1);
    __syncthreads();
    bf16x8v av[4], bv[4];
    #pragma unroll
    for(int f = 0; f < 4; f++){
      av[f] = *(const bf16x8v*)(As + (wm*64 + f*16 + r16) * 32 + kh * 8);
      bv[f] = *(const bf16x8v*)(Bs + (wn*64 + f*16 + r16) * 32 + kh * 8);
    }
    #pragma unroll
    for(int i = 0; i < 4; i++)
      #pragma unroll
      for(int j = 0; j < 4; j++)
        acc[i][j] = __builtin_amdgcn_mfma_f32_16x16x32_bf16(av[i], bv[j], acc[i][j], 0, 0, 0);
  }

  const int crow0 = row0 + wm * 64;
  const int ccol0 = col0 + wn * 64;

  if constexpr(EPI != EPI_LOGITS){
    float part = 0.f;
    #pragma unroll
    for(int i = 0; i < 4; i++){
      #pragma unroll
      for(int j = 0; j < 4; j++){
        const int col = ccol0 + j*16 + r16;
        const float bvv = bias ? bias[col] : 0.f;
        #pragma unroll
        for(int q = 0; q < 4; q++){
          const int row = crow0 + i*16 + kh*4 + q;
          const float v = acc[i][j][q] + bvv;
          const size_t off = (size_t)row * ldc + col;
          if constexpr(EPI == EPI_GELU){
            outb[off] = f2bf(gelu_exact(v));
          } else if constexpr(EPI == EPI_SB){
            const float t = 0.25f * tanhf(v);
            outf[off] = t + addv;
            part += t * t;
          } else if constexpr(EPI == EPI_TL){
            outf[off] = v * TINV;
          } else {                      // EPI_RAW: bf16 out, l2norm later
            outb[off] = f2bf(v);
          }
        }
      }
    }
    if constexpr(EPI == EPI_SB){
      const float tot2 = block_sum(part, rbuf);
      if(tid == 0)
        aux[(size_t)blockIdx.z * (gridDim.x * gridDim.y) + by * gridDim.x + bx] = tot2;
    }
  } else {
    // logits tile: e = exp(10*acc); deterministic row/col partial sums
    float rs[16], cs[4];
    #pragma unroll
    for(int t = 0; t < 16; t++) rs[t] = 0.f;
    #pragma unroll
    for(int t = 0; t < 4; t++) cs[t] = 0.f;
    #pragma unroll
    for(int i = 0; i < 4; i++)
      #pragma unroll
      for(int j = 0; j < 4; j++)
        #pragma unroll
        for(int q = 0; q < 4; q++){
          const float ev = expf(acc[i][j][q] * TINV);
          rs[i*4 + q] += ev;
          cs[j]       += ev;
        }
    #pragma unroll
    for(int t = 0; t < 16; t++){
      float r = rs[t];
      r += __shfl_xor(r, 1); r += __shfl_xor(r, 2);
      r += __shfl_xor(r, 4); r += __shfl_xor(r, 8);
      rs[t] = r;
    }
    if(r16 == 0){
      #pragma unroll
      for(int i = 0; i < 4; i++)
        #pragma unroll
        for(int q = 0; q < 4; q++)
          rbuf[wn*128 + wm*64 + i*16 + kh*4 + q] = rs[i*4 + q];
    }
    #pragma unroll
    for(int j = 0; j < 4; j++){
      float c = cs[j];
      c += __shfl_xor(c, 16); c += __shfl_xor(c, 32);
      cs[j] = c;
    }
    if(kh == 0){
      #pragma unroll
      for(int j = 0; j < 4; j++)
        rbuf[256 + wm*128 + wn*64 + j*16 + r16] = cs[j];
    }
    __syncthreads();
    if(tid < 128){
      aux [(size_t)bx * M + row0 + tid] = rbuf[tid]       + rbuf[128 + tid];
      aux2[(size_t)by * M + col0 + tid] = rbuf[256 + tid] + rbuf[384 + tid];
    }
  }
}

// ---------------- aligned = scale*latent + bias (all f32) --------------------
__global__ __launch_bounds__(256)
void aligned_kernel(const float* __restrict__ latent, const float* __restrict__ sc,
                    const float* __restrict__ bi, float* __restrict__ outp){
  const size_t i4 = ((size_t)blockIdx.x * 256 + threadIdx.x) * 4;
  const float4 l = *(const float4*)(latent + i4);
  float4 o;
  o.x = sc[i4+0] * l.x + bi[i4+0];
  o.y = sc[i4+1] * l.y + bi[i4+1];
  o.z = sc[i4+2] * l.z + bi[i4+2];
  o.w = sc[i4+3] * l.w + bi[i4+3];
  *(float4*)(outp + i4) = o;
}

// ---------------- in-place row l2-normalize (bf16) ---------------------------
__global__ __launch_bounds__(256)
void l2n_kernel(bf16* __restrict__ vio){
  __shared__ float buf[4];
  const int row = blockIdx.x, tid = threadIdx.x;
  const size_t base = (size_t)row * HD;
  float v[3];
  #pragma unroll
  for(int j = 0; j < 3; j++) v[j] = bf2f(vio[base + tid + j*256]);
  float q = v[0]*v[0] + v[1]*v[1] + v[2]*v[2];
  q = block_sum(q, buf);
  const float inv = 1.0f / fmaxf(sqrtf(q), 1e-12f);
  #pragma unroll
  for(int j = 0; j < 3; j++) vio[base + tid + j*256] = f2bf(v[j] * inv);
}

// ---------------- diag_i = 10 * dot(va_i, vb_i) ------------------------------
__global__ __launch_bounds__(256)
void diag_kernel(const bf16* __restrict__ va, const bf16* __restrict__ vb,
                 float* __restrict__ diag){
  const int lane = threadIdx.x & 63;
  const int row = blockIdx.x * 4 + (threadIdx.x >> 6);
  const size_t base = (size_t)row * HD;
  float d = 0.f;
  #pragma unroll
  for(int j = 0; j < 12; j++){
    const int i = lane + j*64;
    d += bf2f(va[base + i]) * bf2f(vb[base + i]);
  }
  #pragma unroll
  for(int o = 32; o; o >>= 1) d += __shfl_down(d, o);
  if(lane == 0) diag[row] = d * TINV;
}

// ---------------- sum 64 partials per row/col --------------------------------
__global__ __launch_bounds__(256)
void rcsum_kernel(const float* __restrict__ rp, const float* __restrict__ cp,
                  float* __restrict__ rs, float* __restrict__ cs, const int nb){
  const int i = blockIdx.x * 256 + threadIdx.x;
  float r = 0.f, c = 0.f;
  for(int b = 0; b < nb; b++){
    r += rp[(size_t)b * NRr + i];
    c += cp[(size_t)b * NRr + i];
  }
  rs[i] = r; cs[i] = c;
}

// ------- gather sampled rows (f32 raw) + l2-normalized bf16 ------------------
__global__ __launch_bounds__(256)
void af_kernel(const float* __restrict__ aligned, const int* __restrict__ samp,
               float* __restrict__ afraw, bf16* __restrict__ afn){
  __shared__ float buf[4];
  const int s = blockIdx.x, tid = threadIdx.x;
  const size_t src = (size_t)samp[s] * HD, dst = (size_t)s * HD;
  float v[3];
  #pragma unroll
  for(int j = 0; j < 3; j++){
    const int i = tid + j*256;
    v[j] = aligned[src + i];
    afraw[dst + i] = v[j];
  }
  float q = v[0]*v[0] + v[1]*v[1] + v[2]*v[2];
  q = block_sum(q, buf);
  const float inv = 1.0f / fmaxf(sqrtf(q), 1e-12f);
  #pragma unroll
  for(int j = 0; j < 3; j++) afn[dst + tid + j*256] = f2bf(v[j] * inv);
}

// ------- gather token pool rows (f32 raw) + l2-normalized bf16 ---------------
__global__ __launch_bounds__(256)
void te_kernel(const float* __restrict__ emb, const int* __restrict__ tok,
               float* __restrict__ teg, bf16* __restrict__ ten){
  __shared__ float buf[4];
  const int p = blockIdx.x, tid = threadIdx.x;
  const size_t src = (size_t)tok[p] * HD, dst = (size_t)p * HD;
  float v[3];
  #pragma unroll
  for(int j = 0; j < 3; j++){
    const int i = tid + j*256;
    v[j] = emb[src + i];
    teg[dst + i] = v[j];
  }
  float q = v[0]*v[0] + v[1]*v[1] + v[2]*v[2];
  q = block_sum(q, buf);
  const float inv = 1.0f / fmaxf(sqrtf(q), 1e-12f);
  #pragma unroll
  for(int j = 0; j < 3; j++) ten[dst + tid + j*256] = f2bf(v[j] * inv);
}

// ---------------- per-row top-64 -> softmax -> proto -> (af-proto)^2 ---------
__global__ __launch_bounds__(256)
void topk_kernel(const float* __restrict__ tl, const float* __restrict__ teg,
                 const float* __restrict__ afraw, float* __restrict__ protopart){
  __shared__ float sv[NPOOL];
  __shared__ float topv[KTOP];
  __shared__ int   topi[KTOP];
  __shared__ float wts[KTOP];
  __shared__ float rv[4];
  __shared__ int   ri[4];
  __shared__ float buf[4];
  __shared__ float sinv;
  const int s = blockIdx.x, tid = threadIdx.x;
  const int lane = tid & 63, w = tid >> 6;
  #pragma unroll
  for(int j = 0; j < 4; j++) sv[tid + j*256] = tl[(size_t)s * NPOOL + tid + j*256];
  __syncthreads();
  for(int k = 0; k < KTOP; k++){
    float bvv = -1e30f; int bi = 0x7fffffff;
    #pragma unroll
    for(int j = 0; j < 4; j++){
      const int i = tid + j*256;
      const float x = sv[i];
      if(x > bvv || (x == bvv && i < bi)){ bvv = x; bi = i; }
    }
    #pragma unroll
    for(int o = 1; o < 64; o <<= 1){
      const float ov = __shfl_xor(bvv, o);
      const int   oi = __shfl_xor(bi, o);
      if(ov > bvv || (ov == bvv && oi < bi)){ bvv = ov; bi = oi; }
    }
    if(lane == 0){ rv[w] = bvv; ri[w] = bi; }
    __syncthreads();
    if(tid == 0){
      for(int w2 = 1; w2 < 4; w2++)
        if(rv[w2] > bvv || (rv[w2] == bvv && ri[w2] < bi)){ bvv = rv[w2]; bi = ri[w2]; }
      if(bi < 0 || bi >= NPOOL) bi = 0;   // NaN-safe: never write OOB
      topv[k] = bvv; topi[k] = bi; sv[bi] = -1e30f;
    }
    __syncthreads();
  }
  if(tid < KTOP) wts[tid] = expf(topv[tid] - topv[0]);
  __syncthreads();
  if(tid == 0){
    float t = 0.f;
    for(int k = 0; k < KTOP; k++) t += wts[k];
    sinv = 1.0f / t;
  }
  __syncthreads();
  float part = 0.f;
  #pragma unroll
  for(int j = 0; j < 3; j++){
    const int h = tid + j*256;
    float ph = 0.f;
    for(int k = 0; k < KTOP; k++) ph += wts[k] * teg[(size_t)topi[k] * HD + h];
    ph *= sinv;
    const float d = afraw[(size_t)s * HD + h] - ph;
    part += d * d;
  }
  part = block_sum(part, buf);
  if(tid == 0) protopart[s] = part;
}

// ------- column moments, stage 1: 32 blocks x 40 rows of [af(256); te(1024)] -
__global__ __launch_bounds__(768)
void mom1_kernel(const float* __restrict__ afraw, const float* __restrict__ teg,
                 float* __restrict__ partial){
  const int b = blockIdx.x, h = threadIdx.x;
  float sa = 0.f, sa2 = 0.f, st = 0.f, st2 = 0.f;
  for(int r = b * 40; r < b * 40 + 40; r++){
    if(r < SSAMP){
      const float v = afraw[(size_t)r * HD + h];
      sa += v; sa2 += v * v;
    } else {
      const float v = teg[(size_t)(r - SSAMP) * HD + h];
      st += v; st2 += v * v;
    }
  }
  partial[(size_t)(b*4 + 0) * HD + h] = sa;
  partial[(size_t)(b*4 + 1) * HD + h] = sa2;
  partial[(size_t)(b*4 + 2) * HD + h] = st;
  partial[(size_t)(b*4 + 3) * HD + h] = st2;
}

// ------- column moments, stage 2 ---------------------------------------------
__global__ __launch_bounds__(768)
void mom2_kernel(const float* __restrict__ partial, float* __restrict__ mom){
  __shared__ float buf[12];
  const int h = threadIdx.x;
  float sa = 0.f, sa2 = 0.f, st = 0.f, st2 = 0.f;
  for(int b = 0; b < 32; b++){
    sa  += partial[(size_t)(b*4 + 0) * HD + h];
    sa2 += partial[(size_t)(b*4 + 1) * HD + h];
    st  += partial[(size_t)(b*4 + 2) * HD + h];
    st2 += partial[(size_t)(b*4 + 3) * HD + h];
  }
  const float ma  = sa * (1.0f / SSAMP);
  const float sda = sqrtf(fmaxf(sa2 * (1.0f / SSAMP) - ma * ma, 0.f));
  const float mt  = st * (1.0f / NPOOL);
  const float sdt = sqrtf(fmaxf(st2 * (1.0f / NPOOL) - mt * mt, 0.f));
  const float dmu = ma - mt, dsd = sda - sdt;
  const float t1 = block_sum(dmu * dmu, buf);
  const float t2 = block_sum(dsd * dsd, buf);
  if(h == 0){ mom[0] = t1; mom[1] = t2; }
}

// ---------------- final scalars (f32 out) ------------------------------------
__global__ __launch_bounds__(1024)
void final_kernel(const float* __restrict__ rs, const float* __restrict__ cs,
                  const float* __restrict__ diag,
                  const float* __restrict__ aux, const int naux,
                  const float* __restrict__ protopart, const float* __restrict__ mom,
                  float* __restrict__ outsc){
  __shared__ float buf[16];
  const int tid = threadIdx.x;
  float s1 = 0.f, s2 = 0.f;
  for(int r = tid; r < NRr; r += 1024){
    const float dg = diag[r];
    s1 += logf(rs[r]) - dg;
    s2 += logf(cs[r]) - dg;
  }
  float c1 = 0.f;
  for(int j = tid; j < naux; j += 1024) c1 += aux[j];
  float pp = 0.f;
  for(int j = tid; j < SSAMP; j += 1024) pp += protopart[j];
  s1 = block_sum(s1, buf);
  s2 = block_sum(s2, buf);
  c1 = block_sum(c1, buf);
  pp = block_sum(pp, buf);
  if(tid == 0){
    const float con  = 0.5f * (s1 + s2) / (float)NRr;
    const float creg = c1 / 6291456.0f;
    const float tdl  = pp / (float)(SSAMP * HD) + 0.1f * ((mom[0] + mom[1]) / (float)HD);
    outsc[0] = con;
    outsc[1] = tdl;
    outsc[2] = creg;
  }
}

// =================================================================== host ====
extern "C" void kernel_launch(void* const* d_in, const int* in_sizes, int n_in,
                              void* d_out, int out_size, void* d_ws, size_t ws_size,
                              hipStream_t stream){
  (void)in_sizes; (void)n_in; (void)out_size; (void)ws_size;
  const float* latent = (const float*)d_in[0];
  const float* tokemb = (const float*)d_in[1];
  const float* s_g  = (const float*)d_in[2];  const float* s_bln = (const float*)d_in[3];
  const float* s_w1 = (const float*)d_in[4];  const float* s_b1  = (const float*)d_in[5];
  const float* s_w2 = (const float*)d_in[6];  const float* s_b2  = (const float*)d_in[7];
  const float* b_g  = (const float*)d_in[8];  const float* b_bln = (const float*)d_in[9];
  const float* b_w1 = (const float*)d_in[10]; const float* b_b1  = (const float*)d_in[11];
  const float* b_w2 = (const float*)d_in[12]; const float* b_b2  = (const float*)d_in[13];
  const float* c_g  = (const float*)d_in[14]; const float* c_bln = (const float*)d_in[15];
  const float* c_w1 = (const float*)d_in[16]; const float* c_b1  = (const float*)d_in[17];
  const float* c_w2 = (const float*)d_in[18]; const float* c_b2  = (const float*)d_in[19];
  const float* noise_a = (const float*)d_in[20];
  const float* noise_b = (const float*)d_in[21];
  const int*  samp = (const int*)d_in[22];
  const int*  tok  = (const int*)d_in[23];

  float* out = (float*)d_out;
  float* out_aligned = out;                                   // [NRr*HD]
  float* out_scalars = out + (size_t)NRr * HD;                // [3]
  float* out_scale   = out + (size_t)NRr * HD + 3;            // [NRr*HD]
  float* out_bias    = out_scale + (size_t)NRr * HD;          // [NRr*HD]

  // ---- workspace (~66.7 MB, phase-checked aliases) ----
  char* wp = (char*)d_ws;
  auto alloc = [&](size_t bytes) -> char* {
    char* p = wp; wp += (bytes + 255) & ~(size_t)255; return p;
  };
  bf16* wt_comb1 = (bf16*)alloc((size_t)2*HD*HD*2);   // [1536][768] diag(g)w1 for s|b
  bf16* wt_c1    = (bf16*)alloc((size_t)HD*HD*2);     // diag(c_g) c_w1
  bf16* wt_s2    = (bf16*)alloc((size_t)HD*HD*2);
  bf16* wt_b2    = (bf16*)alloc((size_t)HD*HD*2);
  bf16* wt_c2    = (bf16*)alloc((size_t)HD*HD*2);
  float* bcomb1  = (float*)alloc(2*HD*4);             // folded bias for s|b GEMM1
  float* bc1     = (float*)alloc(HD*4);               // folded bias for c GEMM1
  bf16* A1 = (bf16*)alloc((size_t)2*NRr*HD*2);        // 25.2MB multi-use
  bf16* A2 = (bf16*)alloc((size_t)2*NRr*HD*2);        // 25.2MB multi-use
  float* rowpart = (float*)alloc((size_t)64*NRr*4);
  float* colpart = (float*)alloc((size_t)64*NRr*4);
  float* rowsum  = (float*)alloc((size_t)NRr*4);
  float* colsum  = (float*)alloc((size_t)NRr*4);
  float* diag    = (float*)alloc((size_t)NRr*4);
  float* aux     = (float*)alloc(768*4);
  float* afraw   = (float*)alloc((size_t)SSAMP*HD*4);
  float* teg     = (float*)alloc((size_t)NPOOL*HD*4);
  float* tlb     = (float*)alloc((size_t)SSAMP*NPOOL*4);
  float* protopart = (float*)alloc(SSAMP*4);
  float* mom     = (float*)alloc(2*4);
  // aliases (phase-disjoint): rowpart/colpart dead after rcsum; af/te/mom run after
  float* mompart = rowpart;                 // 32*4*768 f32 = 0.39MB <= 2.1MB
  bf16*  ten     = (bf16*)colpart;          // 1024*768 bf16 = 1.57MB
  bf16*  afn     = (bf16*)(colpart + ((size_t)NPOOL*HD*2)/4); // 0.39MB, after ten

  const dim3 tb(32, 8), tg(24, 24);
  // weight prep: fold LN affine into GEMM1 weights/biases
  tscale768<<<tg, tb, 0, stream>>>(s_w1, s_g, wt_comb1);
  tscale768<<<tg, tb, 0, stream>>>(b_w1, b_g, wt_comb1 + (size_t)HD*HD);
  tscale768<<<tg, tb, 0, stream>>>(c_w1, c_g, wt_c1);
  tscale768<<<tg, tb, 0, stream>>>(s_w2, nullptr, wt_s2);
  tscale768<<<tg, tb, 0, stream>>>(b_w2, nullptr, wt_b2);
  tscale768<<<tg, tb, 0, stream>>>(c_w2, nullptr, wt_c2);
  foldbias<<<3, 256, 0, stream>>>(s_bln, s_w1, s_b1, bcomb1);
  foldbias<<<3, 256, 0, stream>>>(b_bln, b_w1, b_b1, bcomb1 + HD);
  foldbias<<<3, 256, 0, stream>>>(c_bln, c_w1, c_b1, bc1);

  // scale+bias heads: one xh LN, one N=1536 GEMM1, one z=2 GEMM2
  lnxh_kernel<<<NRr, 256, 0, stream>>>(latent, nullptr, nullptr, A2);
  gemm_kernel<EPI_GELU><<<dim3(12,64), 256, 0, stream>>>(
      A2, wt_comb1, nullptr, NRr, 2*HD, HD, HD, 2*HD, bcomb1, nullptr,
      A1, nullptr, nullptr, nullptr, nullptr);
  gemm_kernel<EPI_SB><<<dim3(6,64,2), 256, 0, stream>>>(
      A1, wt_s2, wt_b2, NRr, HD, HD, 2*HD, HD, s_b2, b_b2,
      nullptr, out_scale, out_bias, aux, nullptr);
  aligned_kernel<<<(NRr * HD) / (256 * 4), 256, 0, stream>>>(latent, out_scale, out_bias, out_aligned);

  // contrastive heads a|b stacked (16384 rows)
  lnxh_kernel<<<2*NRr, 256, 0, stream>>>(out_aligned, noise_a, noise_b, A1);
  gemm_kernel<EPI_GELU><<<dim3(6,128), 256, 0, stream>>>(
      A1, wt_c1, nullptr, 2*NRr, HD, HD, HD, HD, bc1, nullptr,
      A2, nullptr, nullptr, nullptr, nullptr);
  gemm_kernel<EPI_RAW><<<dim3(6,128), 256, 0, stream>>>(
      A2, wt_c2, nullptr, 2*NRr, HD, HD, HD, HD, c_b2, nullptr,
      A1, nullptr, nullptr, nullptr, nullptr);
  l2n_kernel<<<2*NRr, 256, 0, stream>>>(A1);
  bf16* va = A1;
  bf16* vb = A1 + (size_t)NRr * HD;

  // streaming logits LSE
  gemm_kernel<EPI_LOGITS><<<dim3(64,64), 256, 0, stream>>>(
      va, vb, nullptr, NRr, NRr, HD, HD, 0, nullptr, nullptr,
      nullptr, nullptr, nullptr, rowpart, colpart);
  rcsum_kernel<<<NRr / 256, 256, 0, stream>>>(rowpart, colpart, rowsum, colsum, NRr / 128);
  diag_kernel<<<NRr / 4, 256, 0, stream>>>(va, vb, diag);

  // token distribution path
  af_kernel<<<SSAMP, 256, 0, stream>>>(out_aligned, samp, afraw, afn);
  te_kernel<<<NPOOL, 256, 0, stream>>>(tokemb, tok, teg, ten);
  gemm_kernel<EPI_TL><<<dim3(8,2), 256, 0, stream>>>(
      afn, ten, nullptr, SSAMP, NPOOL, HD, HD, NPOOL, nullptr, nullptr,
      nullptr, tlb, nullptr, nullptr, nullptr);
  topk_kernel<<<SSAMP, 256, 0, stream>>>(tlb, teg, afraw, protopart);
  mom1_kernel<<<32, 768, 0, stream>>>(afraw, teg, mompart);
  mom2_kernel<<<1, 768, 0, stream>>>(mompart, mom);

  final_kernel<<<1, 1024, 0, stream>>>(rowsum, colsum, diag, aux, 768,
                                       protopart, mom, out_scalars);
}